// Round 5
// baseline (338.479 us; speedup 1.0000x reference)
//
#include <hip/hip_runtime.h>
#include <cstdint>
#include <cstddef>

// ---------- types ----------
typedef __bf16 bf16x8 __attribute__((ext_vector_type(8)));
typedef float  f32x4  __attribute__((ext_vector_type(4)));
typedef unsigned short us8 __attribute__((ext_vector_type(8)));
typedef unsigned short us4 __attribute__((ext_vector_type(4)));

__device__ __forceinline__ unsigned short f2bf(float f) {
  union { float f; unsigned u; } v; v.f = f;
  unsigned r = v.u + 0x7FFFu + ((v.u >> 16) & 1u);
  return (unsigned short)(r >> 16);
}
__device__ __forceinline__ float b2f(unsigned short h) {
  union { unsigned u; float f; } v; v.u = ((unsigned)h) << 16;
  return v.f;
}
__device__ __forceinline__ f32x4 mfma16(bf16x8 a, bf16x8 b, f32x4 c) {
  return __builtin_amdgcn_mfma_f32_16x16x32_bf16(a, b, c, 0, 0, 0);
}
// async global->LDS, 16B per lane; lds dest wave-uniform (HW writes base + lane*16)
__device__ __forceinline__ void gl_lds16(const unsigned short* g, unsigned short* l) {
  __builtin_amdgcn_global_load_lds(
      (const __attribute__((address_space(1))) void*)g,
      (__attribute__((address_space(3))) void*)l, 16, 0, 0);
}

// ---------- misc prep: bias concat, rope tables, zero-pad ----------
__global__ void prep_misc_kernel(const float* __restrict__ b_qkv,
                                 const float* __restrict__ b_kpos,
                                 const float* __restrict__ b_qup,
                                 const float* __restrict__ b_qpos,
                                 float* __restrict__ bias1,
                                 float* __restrict__ bias2q,
                                 float* __restrict__ costab,
                                 float* __restrict__ sintab,
                                 unsigned short* __restrict__ wB1pad) {
  int i = blockIdx.x * 256 + threadIdx.x;   // grid covers 131072
  if (i < 65536) {                          // 2048 x 32 rope tables
    int s = i >> 5, f = i & 31;
    float inv = powf(50000.0f, -(float)f / 32.0f);
    float a = (float)s * inv;
    costab[i] = cosf(a);
    sintab[i] = sinf(a);
  }
  if (i < 1664) bias1[i] = (i < 1536) ? b_qkv[i] : (i < 1600 ? b_kpos[i - 1536] : 0.0f);
  if (i < 3072) bias2q[i] = (i < 2048) ? b_qup[i] : b_qpos[i - 2048];
  if (i < 131072) wB1pad[i] = 0;            // rows 1600..1663 of wB1
}

// ---------- x fp32 -> bf16 ----------
__global__ void convx_kernel(const float* __restrict__ in,
                             unsigned short* __restrict__ out, int n4) {
  int i = blockIdx.x * 256 + threadIdx.x;
  if (i < n4) {
    float4 v = ((const float4*)in)[i];
    us4 o;
    o[0] = f2bf(v.x); o[1] = f2bf(v.y); o[2] = f2bf(v.z); o[3] = f2bf(v.w);
    ((us4*)out)[i] = o;
  }
}

// ---------- weight transpose + convert: out[c*ldo + r] = bf16(in[r*ldin + c]) ----------
__global__ void tconv_kernel(const float* __restrict__ in, int ldin,
                             unsigned short* __restrict__ out, int ldo) {
  __shared__ float tile[32][33];
  int c0 = blockIdx.x * 32, r0 = blockIdx.y * 32;
  int tx = threadIdx.x & 31, ty = threadIdx.x >> 5;
  for (int j = 0; j < 4; ++j)
    tile[ty + j * 8][tx] = in[(size_t)(r0 + ty + j * 8) * ldin + c0 + tx];
  __syncthreads();
  for (int j = 0; j < 4; ++j)
    out[(size_t)(c0 + ty + j * 8) * ldo + r0 + tx] = f2bf(tile[tx][ty + j * 8]);
}

// ---------- GEMM: C[M,N] = A[M,K]*Bt[N,K]^T + bias ----------
// OUT_MODE: 0 = bf16 row-major, 1 = f32 row-major, 2 = bf16 transposed (vT epilogue).
// 128x128 tile, BK=64, global_load_lds w16 with pre-swizzled source, swizzled ds_read.
template <int OUT_MODE>
__global__ __launch_bounds__(256, 2)
void gemm_bt_kernel(const unsigned short* __restrict__ A, int lda,
                    const unsigned short* __restrict__ Bt, int ldb,
                    void* __restrict__ Cout, int ldc,
                    const float* __restrict__ bias, int K) {
  __shared__ unsigned short smem[OUT_MODE == 2 ? 128 * 136 : 128 * 128];
  unsigned short* Alds = smem;               // [128][64] shorts, 16B-block-swizzled
  unsigned short* Blds = smem + 128 * 64;
  int tid = threadIdx.x;
  int wave = tid >> 6, lane = tid & 63;
  int g = lane >> 4, r = lane & 15;
  int wr = wave >> 1, wc = wave & 1;
  long brow = (long)blockIdx.y * 128, bcol = (long)blockIdx.x * 128;

  // staging: wave w stages rows [w*32, w*32+32); each gl_lds call covers 8 rows.
  // LDS linear dest; swizzle on the GLOBAL source col: blk16 b of row holds b ^ (row&7).
  int srowl = lane >> 3;                        // 0..7 within the 8-row call
  int sw = ((lane & 7) ^ (srowl & 7)) * 8;      // swizzled col offset (shorts)
  const unsigned short* Abase = A + (brow + wave * 32 + srowl) * (long)lda + sw;
  const unsigned short* Bbase = Bt + (bcol + wave * 32 + srowl) * (long)ldb + sw;

  f32x4 acc[4][4];
  for (int mi = 0; mi < 4; ++mi)
    for (int ni = 0; ni < 4; ++ni)
      acc[mi][ni] = f32x4{0.f, 0.f, 0.f, 0.f};

  const char* Ab = (const char*)Alds;
  const char* Bb = (const char*)Blds;
  int rx = (r & 7) << 4;

  for (int k0 = 0; k0 < K; k0 += 64) {
    for (int c = 0; c < 4; ++c) {
      gl_lds16(Abase + (size_t)c * 8 * lda + k0, Alds + (wave * 32 + c * 8) * 64);
      gl_lds16(Bbase + (size_t)c * 8 * ldb + k0, Blds + (wave * 32 + c * 8) * 64);
    }
    __syncthreads();   // drains vmcnt -> LDS tile ready
    for (int kk = 0; kk < 2; ++kk) {
      bf16x8 af[4], bfv[4];
      for (int mi = 0; mi < 4; ++mi)
        af[mi] = *(const bf16x8*)(Ab + (size_t)(wr * 64 + mi * 16 + r) * 128 +
                                  ((kk * 64 + g * 16) ^ rx));
      for (int ni = 0; ni < 4; ++ni)
        bfv[ni] = *(const bf16x8*)(Bb + (size_t)(wc * 64 + ni * 16 + r) * 128 +
                                   ((kk * 64 + g * 16) ^ rx));
      for (int mi = 0; mi < 4; ++mi)
        for (int ni = 0; ni < 4; ++ni)
          acc[mi][ni] = mfma16(af[mi], bfv[ni], acc[mi][ni]);
    }
    __syncthreads();   // LDS free for next tile
  }

  if (OUT_MODE == 2) {
    // transposed epilogue -> vT[bh][d][s]; Cout = vT base, N=2048, M=4096.
    for (int mi = 0; mi < 4; ++mi)
      for (int ni = 0; ni < 4; ++ni) {
        int col = wc * 64 + ni * 16 + r;
        float bv = bias[bcol + col];
        int rowb = wr * 64 + mi * 16 + g * 4;
        for (int i = 0; i < 4; ++i)
          smem[col * 136 + rowb + i] = f2bf(acc[mi][ni][i] + bv);
      }
    __syncthreads();
    int col = tid >> 1, half = tid & 1;
    int bh = (int)(brow >> 11) * 16 + (int)(bcol >> 7);
    unsigned short* outp = (unsigned short*)Cout +
                           ((size_t)bh * 128 + col) * 2048 + (brow & 2047);
    for (int j = 0; j < 8; ++j) {
      int row0 = half * 64 + j * 8;
      *(us8*)(outp + row0) = *(const us8*)&smem[col * 136 + row0];
    }
    return;
  }

  for (int mi = 0; mi < 4; ++mi)
    for (int ni = 0; ni < 4; ++ni) {
      long col = bcol + wc * 64 + ni * 16 + r;
      float bv = bias ? bias[col] : 0.0f;
      long rowb = brow + wr * 64 + mi * 16 + g * 4;
      for (int i = 0; i < 4; ++i) {
        float v = acc[mi][ni][i] + bv;
        if (OUT_MODE == 1)
          ((float*)Cout)[(rowb + i) * (long)ldc + col] = v;
        else
          ((unsigned short*)Cout)[(rowb + i) * (long)ldc + col] = f2bf(v);
      }
    }
}

// ---------- rope: posqr[4096][1024] (per-head 64) and poskr[4096][64], vectorized ----------
__global__ void rope_kernel(const unsigned short* __restrict__ tmp_q,
                            const unsigned short* __restrict__ latext,
                            const float* __restrict__ costab,
                            const float* __restrict__ sintab,
                            unsigned short* __restrict__ posqr,
                            unsigned short* __restrict__ poskr) {
  int idx = blockIdx.x * 256 + threadIdx.x;  // 524288 posq + 32768 posk = 557056
  const unsigned short* src;
  unsigned short* dst;
  int s, dp0;
  if (idx < 524288) {
    int rowA = idx >> 7, rem = idx & 127;    // rem = h*8 + dpblk
    int h = rem >> 3;
    dp0 = (rem & 7) * 8;
    s = rowA & 2047;
    src = tmp_q + (size_t)rowA * 3072 + 2048 + h * 64;
    dst = posqr + (size_t)rowA * 1024 + h * 64 + dp0;
  } else if (idx < 557056) {
    int j = idx - 524288;
    int rowA = j >> 3;
    dp0 = (j & 7) * 8;
    s = rowA & 2047;
    src = latext + (size_t)rowA * 1664 + 1536;
    dst = poskr + (size_t)rowA * 64 + dp0;
  } else {
    return;
  }
  us8 x1 = *(const us8*)(src + dp0);
  us8 x2 = *(const us8*)(src + (dp0 ^ 32));
  int f0 = dp0 & 31;
  const float* cp = costab + s * 32 + f0;
  const float* sp = sintab + s * 32 + f0;
  bool low = dp0 < 32;
  us8 o;
  for (int e = 0; e < 8; ++e) {
    float a = b2f(x1[e]), b = b2f(x2[e]);
    float v = low ? (a * cp[e] - b * sp[e]) : (a * cp[e] + b * sp[e]);
    o[e] = f2bf(v);
  }
  *(us8*)dst = o;
}

// ---------- task decode: 2560 tasks, longest-first ----------
// band0 t<1024:  qt 31..24, 4 segs; band1 <1792: qt 23..16, 3 segs;
// band2 <2304: qt 15..8, 2 segs; band3 <2560: qt 7..0, 1 seg.
__device__ __forceinline__ void task_decode(int t, int& qt, int& seg, int& bh) {
  if (t < 1024) {
    qt = 31 - (t >> 7); int rem = t & 127; seg = rem >> 5; bh = rem & 31;
  } else if (t < 1792) {
    int t2 = t - 1024; int qi = t2 / 96; int rem = t2 - qi * 96;
    qt = 23 - qi; seg = rem >> 5; bh = rem & 31;
  } else if (t < 2304) {
    int t3 = t - 1792; qt = 15 - (t3 >> 6); int rem = t3 & 63; seg = rem >> 5; bh = rem & 31;
  } else {
    int t4 = t - 2304; qt = 7 - (t4 >> 5); seg = 0; bh = t4 & 31;
  }
}
__device__ __forceinline__ int task_slot(int qt, int seg, int bh) {
  if (qt >= 24) return (31 - qt) * 128 + seg * 32 + bh;
  if (qt >= 16) return 1024 + (23 - qt) * 96 + seg * 32 + bh;
  return 1792 + (15 - qt) * 64 + seg * 32 + bh;
}

// ---------- persistent split-KV causal flash attention, dynamic work-stealing ----------
// Tasks = (qt, seg) segments of <=16 KV-chunks (32 rows each), claimed longest-first.
// qt<=7 (single segment): write normalized bf16 directly. Else: bf16 partial + (m,l).
__global__ __launch_bounds__(256, 2)
void flash_kernel(const unsigned short* __restrict__ tmp_q,
                  const unsigned short* __restrict__ tmp_k,
                  const unsigned short* __restrict__ posqr,
                  const unsigned short* __restrict__ poskr,
                  const unsigned short* __restrict__ vT,
                  unsigned short* __restrict__ ob,
                  unsigned short* __restrict__ Opart,
                  float* __restrict__ mlbuf,
                  int* __restrict__ counter) {
  const int S = 2048;
  int tid = threadIdx.x, wave = tid >> 6, lane = tid & 63;
  int g = lane >> 4, r = lane & 15;
  const float sl2 = 1.44269504f / 13.8564064605510183f;  // log2e / sqrt(192)
  const float DEFER = 96.0f;

  __shared__ unsigned short Klds[32 * 192];   // swizzled: blk16 ^= row&7
  __shared__ unsigned short Vlds[128 * 32];   // swizzled: blk16 ^= row&3
  __shared__ unsigned short Plds[4][16][40];
  __shared__ int s_tile;
  char* Kb = (char*)Klds;
  char* Vb = (char*)Vlds;
  int rx7 = (r & 7) << 4, rx3 = (r & 3) << 4;

  // staging slot geometry (task-independent)
  int kn_row[2], kn_seg[2];
  for (int j = 0; j < 2; ++j) {
    int slot = j * 256 + tid;
    kn_row[j] = slot >> 4;
    kn_seg[j] = slot & 15;
  }
  int kr_row = tid >> 3, kr_seg = tid & 7;
  int v_row[2], v_seg[2];
  for (int j = 0; j < 2; ++j) {
    int slot = j * 256 + tid;
    v_row[j] = slot >> 2;
    v_seg[j] = slot & 3;
  }

  for (;;) {
    if (tid == 0) s_tile = atomicAdd(counter, 1);
    __syncthreads();
    int t = s_tile;
    if (t >= 2560) return;
    int qt, seg, bh;
    task_decode(t, qt, seg, bh);
    int b = bh >> 4, h = bh & 15;
    int qbase = qt * 64;
    int cbeg = seg * 16;
    int cend = min(cbeg + 16, 2 * (qt + 1));
    size_t rb = (size_t)b * 2048;

    const unsigned short* kpn = tmp_k + rb * 2048 + h * 128;  // row stride 2048
    const unsigned short* kpr = poskr + rb * 64;              // row stride 64
    const unsigned short* vp = vT + (size_t)bh * 128 * S;

    bf16x8 qf[6];
    {
      size_t qrowA = rb + qbase + wave * 16 + r;
      const unsigned short* qn = tmp_q + qrowA * 3072 + h * 128 + g * 8;
      for (int c = 0; c < 4; ++c) qf[c] = *(const bf16x8*)(qn + c * 32);
      const unsigned short* qr_ = posqr + qrowA * 1024 + h * 64 + g * 8;
      qf[4] = *(const bf16x8*)(qr_);
      qf[5] = *(const bf16x8*)(qr_ + 32);
    }

    f32x4 acc[8];
    for (int d = 0; d < 8; ++d) acc[d] = f32x4{0.f, 0.f, 0.f, 0.f};
    float m_r[4], l_r[4];
    for (int i = 0; i < 4; ++i) { m_r[i] = -3.0e38f; l_r[i] = 0.f; }

    us8 kreg[2], krope, vreg[2];
    {
      int kv0 = cbeg * 32;
      for (int j = 0; j < 2; ++j)
        kreg[j] = *(const us8*)(kpn + (size_t)(kv0 + kn_row[j]) * 2048 + kn_seg[j] * 8);
      krope = *(const us8*)(kpr + (size_t)(kv0 + kr_row) * 64 + kr_seg * 8);
      for (int j = 0; j < 2; ++j)
        vreg[j] = *(const us8*)(vp + (size_t)v_row[j] * S + kv0 + v_seg[j] * 8);
    }

    for (int ch = cbeg; ch < cend; ++ch) {
      for (int j = 0; j < 2; ++j)
        *(us8*)(Kb + (size_t)kn_row[j] * 384 +
                ((kn_seg[j] ^ (kn_row[j] & 7)) << 4)) = kreg[j];
      *(us8*)(Kb + (size_t)kr_row * 384 +
              (((16 + kr_seg) ^ (kr_row & 7)) << 4)) = krope;
      for (int j = 0; j < 2; ++j)
        *(us8*)(Vb + (size_t)v_row[j] * 64 +
                ((v_seg[j] ^ (v_row[j] & 3)) << 4)) = vreg[j];
      __syncthreads();
      if (ch + 1 < cend) {
        int kv1 = (ch + 1) * 32;
        for (int j = 0; j < 2; ++j)
          kreg[j] = *(const us8*)(kpn + (size_t)(kv1 + kn_row[j]) * 2048 + kn_seg[j] * 8);
        krope = *(const us8*)(kpr + (size_t)(kv1 + kr_row) * 64 + kr_seg * 8);
        for (int j = 0; j < 2; ++j)
          vreg[j] = *(const us8*)(vp + (size_t)v_row[j] * S + kv1 + v_seg[j] * 8);
      }
      int kv0 = ch * 32;

      f32x4 sc0 = {0.f, 0.f, 0.f, 0.f}, sc1 = {0.f, 0.f, 0.f, 0.f};
      __builtin_amdgcn_s_setprio(1);
      for (int c = 0; c < 6; ++c) {
        bf16x8 kf0 = *(const bf16x8*)(Kb + (size_t)r * 384 + (((c * 4 + g) << 4) ^ rx7));
        sc0 = mfma16(qf[c], kf0, sc0);
      }
      for (int c = 0; c < 6; ++c) {
        bf16x8 kf1 = *(const bf16x8*)(Kb + (size_t)(16 + r) * 384 + (((c * 4 + g) << 4) ^ rx7));
        sc1 = mfma16(qf[c], kf1, sc1);
      }
      __builtin_amdgcn_s_setprio(0);

      int kj0 = kv0 + r, kj1 = kv0 + 16 + r;
      int qi0 = qbase + wave * 16 + g * 4;
      for (int i = 0; i < 4; ++i) {
        if (kj0 > qi0 + i) sc0[i] = -1e30f;
        if (kj1 > qi0 + i) sc1[i] = -1e30f;
      }

      // T13 defer-max: skip max-tree + rescale when no row grew past m + DEFER
      float tl[4];
      bool ok = true;
      for (int i = 0; i < 4; ++i) {
        tl[i] = fmaxf(sc0[i], sc1[i]);
        ok = ok && (tl[i] - m_r[i] <= DEFER);
      }
      if (!__all(ok)) {
        for (int i = 0; i < 4; ++i) {
          float tm = tl[i];
          for (int off = 1; off < 16; off <<= 1) tm = fmaxf(tm, __shfl_xor(tm, off, 64));
          float mnew = fmaxf(m_r[i], tm);
          float corr = exp2f((m_r[i] - mnew) * sl2);
          l_r[i] *= corr;
          for (int d = 0; d < 8; ++d) acc[d][i] *= corr;
          m_r[i] = mnew;
        }
      }
      float p0[4], p1[4];
      for (int i = 0; i < 4; ++i) {
        float e0 = exp2f((sc0[i] - m_r[i]) * sl2);
        float e1 = exp2f((sc1[i] - m_r[i]) * sl2);
        float rs = e0 + e1;
        for (int off = 1; off < 16; off <<= 1) rs += __shfl_xor(rs, off, 64);
        l_r[i] += rs;
        p0[i] = e0;
        p1[i] = e1;
      }

      for (int i = 0; i < 4; ++i) {
        Plds[wave][g * 4 + i][r] = f2bf(p0[i]);
        Plds[wave][g * 4 + i][16 + r] = f2bf(p1[i]);
      }
      bf16x8 pa = *(const bf16x8*)&Plds[wave][r][g * 8];
      __builtin_amdgcn_s_setprio(1);
      for (int dt = 0; dt < 8; ++dt) {
        bf16x8 vf = *(const bf16x8*)(Vb + (size_t)(dt * 16 + r) * 64 + ((g << 4) ^ rx3));
        acc[dt] = mfma16(pa, vf, acc[dt]);
      }
      __builtin_amdgcn_s_setprio(0);
      __syncthreads();
    }

    if (qt <= 7) {
      // single segment: normalized store
      for (int i = 0; i < 4; ++i) {
        float inv = 1.0f / l_r[i];
        int row = qbase + wave * 16 + g * 4 + i;
        size_t base = (rb + row) * 2048 + h * 128;
        for (int dt = 0; dt < 8; ++dt)
          ob[base + dt * 16 + r] = f2bf(acc[dt][i] * inv);
      }
    } else {
      // bf16 unnormalized partial + (m,l) at slot = task id
      unsigned short* op = Opart + (size_t)t * 8192;
      for (int i = 0; i < 4; ++i) {
        int row = wave * 16 + g * 4 + i;
        for (int dt = 0; dt < 8; ++dt)
          op[row * 128 + dt * 16 + r] = f2bf(acc[dt][i]);
        if (r == 0) {
          mlbuf[(size_t)t * 128 + row * 2]     = m_r[i];
          mlbuf[(size_t)t * 128 + row * 2 + 1] = l_r[i];
        }
      }
    }
  }
}

// ---------- merge partials (qt>=8) -> attn bf16 [B*S, 2048] ----------
__global__ void merge_kernel(const unsigned short* __restrict__ Opart,
                             const float* __restrict__ mlbuf,
                             unsigned short* __restrict__ ob) {
  int qt = 8 + (blockIdx.x >> 5), bh = blockIdx.x & 31;
  int b = bh >> 4, h = bh & 15;
  int tid = threadIdx.x;
  int row = tid >> 2, c0 = (tid & 3) * 32;
  const float sl2 = 1.44269504f / 13.8564064605510183f;
  int ns = (qt >= 24) ? 4 : (qt >= 16 ? 3 : 2);

  size_t slot[4];
  float m[4], l[4], w[4];
  float M = -3.0e38f;
#pragma unroll
  for (int j = 0; j < 4; ++j) {
    if (j < ns) {
      slot[j] = task_slot(qt, j, bh);
      m[j] = mlbuf[slot[j] * 128 + row * 2];
      l[j] = mlbuf[slot[j] * 128 + row * 2 + 1];
      M = fmaxf(M, m[j]);
    }
  }
  float L = 0.f;
#pragma unroll
  for (int j = 0; j < 4; ++j)
    if (j < ns) { w[j] = exp2f((m[j] - M) * sl2); L += w[j] * l[j]; }
  float invL = 1.f / L;
#pragma unroll
  for (int j = 0; j < 4; ++j) if (j < ns) w[j] *= invL;

  float o[32];
#pragma unroll
  for (int e = 0; e < 32; ++e) o[e] = 0.f;
#pragma unroll
  for (int j = 0; j < 4; ++j) {
    if (j < ns) {
      const unsigned short* pp = Opart + slot[j] * 8192 + row * 128 + c0;
      for (int blk = 0; blk < 4; ++blk) {
        us8 v = *(const us8*)(pp + blk * 8);
        for (int e = 0; e < 8; ++e) o[blk * 8 + e] += w[j] * b2f(v[e]);
      }
    }
  }
  size_t obase = ((size_t)b * 2048 + qt * 64 + row) * 2048 + h * 128 + c0;
  for (int blk = 0; blk < 4; ++blk) {
    us8 st;
    for (int e = 0; e < 8; ++e) st[e] = f2bf(o[blk * 8 + e]);
    *(us8*)(ob + obase + blk * 8) = st;
  }
}

// ---------- launcher ----------
extern "C" void kernel_launch(void* const* d_in, const int* in_sizes, int n_in,
                              void* d_out, int out_size, void* d_ws, size_t ws_size,
                              hipStream_t stream) {
  const float* x      = (const float*)d_in[0];
  const float* w_qkv  = (const float*)d_in[1];
  const float* b_qkv  = (const float*)d_in[2];
  const float* w_qup  = (const float*)d_in[3];
  const float* b_qup  = (const float*)d_in[4];
  const float* w_kup  = (const float*)d_in[5];
  const float* b_kup  = (const float*)d_in[6];
  const float* w_vup  = (const float*)d_in[7];
  const float* b_vup  = (const float*)d_in[8];
  const float* w_qpos = (const float*)d_in[9];
  const float* b_qpos = (const float*)d_in[10];
  const float* w_kpos = (const float*)d_in[11];
  const float* b_kpos = (const float*)d_in[12];
  const float* w_o    = (const float*)d_in[13];
  const float* b_o    = (const float*)d_in[14];
  (void)in_sizes; (void)n_in; (void)out_size; (void)ws_size;

  char* ws = (char*)d_ws;
  size_t off = 0;
  auto alloc = [&](size_t bytes) -> char* {
    char* p = ws + off;
    off += (bytes + 255) & ~(size_t)255;
    return p;
  };

  unsigned short* xb     = (unsigned short*)alloc(16777216);  // x bf16 [4096,2048]; reused as attn out
  unsigned short* wB1    = (unsigned short*)alloc(6815744);   // [1664,2048]
  unsigned short* wB2q   = (unsigned short*)alloc(3145728);   // [3072,512]
  unsigned short* wB2k   = (unsigned short*)alloc(2097152);   // [2048,512]
  unsigned short* wB2v   = (unsigned short*)alloc(2097152);   // [2048,512]
  unsigned short* wBo    = (unsigned short*)alloc(8388608);   // [2048,2048]
  float*          bias1  = (float*)alloc(1664 * 4);
  float*          bias2q = (float*)alloc(3072 * 4);
  float*          costab = (float*)alloc(262144);
  float*          sintab = (float*)alloc(262144);
  unsigned short* latext = (unsigned short*)alloc(13631488);  // [4096,1664]
  unsigned short* tmp_q  = (unsigned short*)alloc(25165824);  // [4096,3072]
  unsigned short* tmp_k  = (unsigned short*)alloc(16777216);  // [4096,2048]
  unsigned short* vTbuf  = (unsigned short*)alloc(16777216);  // [32,128,2048]
  unsigned short* posqr  = (unsigned short*)alloc(8388608);   // [4096,1024]
  unsigned short* poskr  = (unsigned short*)alloc(524288);    // [4096,64]
  unsigned short* Opart  = (unsigned short*)alloc(41943040);  // [2560][64][128] bf16
  float*          mlbuf  = (float*)alloc(1310720);            // [2560][64][2]
  int*            counter= (int*)alloc(256);
  unsigned short* attnb  = xb;                                // alias: xb dead after GEMM1

  // 1. misc prep
  prep_misc_kernel<<<512, 256, 0, stream>>>(b_qkv, b_kpos, b_qup, b_qpos,
                                            bias1, bias2q, costab, sintab,
                                            wB1 + (size_t)1600 * 2048);
  // 2. convert x
  convx_kernel<<<8192, 256, 0, stream>>>(x, xb, 2097152);
  // 3. weight transposes (fp32 -> bf16, [K,N] -> [N,K])
  tconv_kernel<<<dim3(48, 64), 256, 0, stream>>>(w_qkv, 1536, wB1, 2048);
  tconv_kernel<<<dim3(2, 64), 256, 0, stream>>>(w_kpos, 64, wB1 + (size_t)1536 * 2048, 2048);
  tconv_kernel<<<dim3(64, 16), 256, 0, stream>>>(w_qup, 2048, wB2q, 512);
  tconv_kernel<<<dim3(32, 16), 256, 0, stream>>>(w_qpos, 1024, wB2q + (size_t)2048 * 512, 512);
  tconv_kernel<<<dim3(64, 16), 256, 0, stream>>>(w_kup, 2048, wB2k, 512);
  tconv_kernel<<<dim3(64, 16), 256, 0, stream>>>(w_vup, 2048, wB2v, 512);
  tconv_kernel<<<dim3(64, 64), 256, 0, stream>>>(w_o, 2048, wBo, 2048);

  // 4. GEMM1: lat_ext[4096,1664] = xb @ wB1^T + bias1  (includes pos_k cols 1536..1599)
  gemm_bt_kernel<0><<<dim3(13, 32), 256, 0, stream>>>(xb, 2048, wB1, 2048,
                                                      latext, 1664, bias1, 2048);
  // 5. up-projections (K=512); v-up writes vT directly (transposed epilogue)
  gemm_bt_kernel<0><<<dim3(24, 32), 256, 0, stream>>>(latext, 1664, wB2q, 512,
                                                      tmp_q, 3072, bias2q, 512);
  gemm_bt_kernel<0><<<dim3(16, 32), 256, 0, stream>>>(latext + 512, 1664, wB2k, 512,
                                                      tmp_k, 2048, b_kup, 512);
  gemm_bt_kernel<2><<<dim3(16, 32), 256, 0, stream>>>(latext + 1024, 1664, wB2v, 512,
                                                      vTbuf, 2048, b_vup, 512);
  // 6. rope (posqr from tmp_q slice, poskr from latext slice)
  rope_kernel<<<2176, 256, 0, stream>>>(tmp_q, latext, costab, sintab, posqr, poskr);
  // 7. persistent split-KV flash attention (work-stealing, 2560 tasks)
  hipMemsetAsync(counter, 0, 4, stream);
  flash_kernel<<<1536, 256, 0, stream>>>(tmp_q, tmp_k, posqr, poskr, vTbuf,
                                         attnb, Opart, mlbuf, counter);
  // 8. merge partials (qt>=8) -> attnb
  merge_kernel<<<768, 256, 0, stream>>>(Opart, mlbuf, attnb);
  // 9. output projection (fp32 out + b_o)
  gemm_bt_kernel<1><<<dim3(16, 32), 256, 0, stream>>>(attnb, 2048, wBo, 2048,
                                                      d_out, 2048, b_o, 2048);
}

// Round 6
// 295.860 us; speedup vs baseline: 1.1441x; 1.1441x over previous
//
#include <hip/hip_runtime.h>
#include <cstdint>
#include <cstddef>

// ---------- types ----------
typedef __bf16 bf16x8 __attribute__((ext_vector_type(8)));
typedef float  f32x4  __attribute__((ext_vector_type(4)));
typedef unsigned short us8 __attribute__((ext_vector_type(8)));
typedef unsigned short us4 __attribute__((ext_vector_type(4)));

__device__ __forceinline__ unsigned short f2bf(float f) {
  union { float f; unsigned u; } v; v.f = f;
  unsigned r = v.u + 0x7FFFu + ((v.u >> 16) & 1u);
  return (unsigned short)(r >> 16);
}
__device__ __forceinline__ float b2f(unsigned short h) {
  union { unsigned u; float f; } v; v.u = ((unsigned)h) << 16;
  return v.f;
}
__device__ __forceinline__ f32x4 mfma16(bf16x8 a, bf16x8 b, f32x4 c) {
  return __builtin_amdgcn_mfma_f32_16x16x32_bf16(a, b, c, 0, 0, 0);
}
// async global->LDS, 16B per lane; lds dest wave-uniform (HW writes base + lane*16)
__device__ __forceinline__ void gl_lds16(const unsigned short* g, unsigned short* l) {
  __builtin_amdgcn_global_load_lds(
      (const __attribute__((address_space(1))) void*)g,
      (__attribute__((address_space(3))) void*)l, 16, 0, 0);
}

// ---------- misc prep: bias concat, rope tables, zero-pad ----------
__global__ void prep_misc_kernel(const float* __restrict__ b_qkv,
                                 const float* __restrict__ b_kpos,
                                 const float* __restrict__ b_qup,
                                 const float* __restrict__ b_qpos,
                                 float* __restrict__ bias1,
                                 float* __restrict__ bias2q,
                                 float* __restrict__ costab,
                                 float* __restrict__ sintab,
                                 unsigned short* __restrict__ wB1pad) {
  int i = blockIdx.x * 256 + threadIdx.x;   // grid covers 131072
  if (i < 65536) {                          // 2048 x 32 rope tables
    int s = i >> 5, f = i & 31;
    float inv = powf(50000.0f, -(float)f / 32.0f);
    float a = (float)s * inv;
    costab[i] = cosf(a);
    sintab[i] = sinf(a);
  }
  if (i < 1664) bias1[i] = (i < 1536) ? b_qkv[i] : (i < 1600 ? b_kpos[i - 1536] : 0.0f);
  if (i < 3072) bias2q[i] = (i < 2048) ? b_qup[i] : b_qpos[i - 2048];
  if (i < 131072) wB1pad[i] = 0;            // rows 1600..1663 of wB1
}

// ---------- x fp32 -> bf16 ----------
__global__ void convx_kernel(const float* __restrict__ in,
                             unsigned short* __restrict__ out, int n4) {
  int i = blockIdx.x * 256 + threadIdx.x;
  if (i < n4) {
    float4 v = ((const float4*)in)[i];
    us4 o;
    o[0] = f2bf(v.x); o[1] = f2bf(v.y); o[2] = f2bf(v.z); o[3] = f2bf(v.w);
    ((us4*)out)[i] = o;
  }
}

// ---------- weight transpose + convert: out[c*ldo + r] = bf16(in[r*ldin + c]) ----------
__global__ void tconv_kernel(const float* __restrict__ in, int ldin,
                             unsigned short* __restrict__ out, int ldo) {
  __shared__ float tile[32][33];
  int c0 = blockIdx.x * 32, r0 = blockIdx.y * 32;
  int tx = threadIdx.x & 31, ty = threadIdx.x >> 5;
  for (int j = 0; j < 4; ++j)
    tile[ty + j * 8][tx] = in[(size_t)(r0 + ty + j * 8) * ldin + c0 + tx];
  __syncthreads();
  for (int j = 0; j < 4; ++j)
    out[(size_t)(c0 + ty + j * 8) * ldo + r0 + tx] = f2bf(tile[tx][ty + j * 8]);
}

// ---------- GEMM: C[M,N] = A[M,K]*Bt[N,K]^T + bias ----------
// OUT_MODE: 0 = bf16 row-major, 1 = f32 row-major, 2 = bf16 transposed (vT epilogue).
// 128x128 tile, BK=64. T3/T4: double-buffered LDS, issue next tile's
// global_load_lds BEFORE computing current, counted s_waitcnt vmcnt(8),
// raw s_barrier (no vmcnt drain).
template <int OUT_MODE>
__global__ __launch_bounds__(256, 2)
void gemm_bt_kernel(const unsigned short* __restrict__ A, int lda,
                    const unsigned short* __restrict__ Bt, int ldb,
                    void* __restrict__ Cout, int ldc,
                    const float* __restrict__ bias, int K) {
  __shared__ unsigned short smem[32768];   // 2 bufs x (A[128][64] + B[128][64])
  int tid = threadIdx.x;
  int wave = tid >> 6, lane = tid & 63;
  int g = lane >> 4, r = lane & 15;
  int wr = wave >> 1, wc = wave & 1;
  long brow = (long)blockIdx.y * 128, bcol = (long)blockIdx.x * 128;

  // staging: wave w stages rows [w*32, w*32+32); each gl_lds call covers 8 rows.
  // LDS linear dest; swizzle on the GLOBAL source col: blk16 b of row holds b ^ (row&7).
  int srowl = lane >> 3;                        // 0..7 within the 8-row call
  int sw = ((lane & 7) ^ (srowl & 7)) * 8;      // swizzled col offset (shorts)
  const unsigned short* Abase = A + (brow + wave * 32 + srowl) * (long)lda + sw;
  const unsigned short* Bbase = Bt + (bcol + wave * 32 + srowl) * (long)ldb + sw;

  f32x4 acc[4][4];
  for (int mi = 0; mi < 4; ++mi)
    for (int ni = 0; ni < 4; ++ni)
      acc[mi][ni] = f32x4{0.f, 0.f, 0.f, 0.f};

  auto stage = [&](int buf, int k0) {
    unsigned short* ab = smem + buf * 16384;
    unsigned short* bb = ab + 8192;
    for (int c = 0; c < 4; ++c) {
      gl_lds16(Abase + (size_t)c * 8 * lda + k0, ab + (wave * 32 + c * 8) * 64);
      gl_lds16(Bbase + (size_t)c * 8 * ldb + k0, bb + (wave * 32 + c * 8) * 64);
    }
  };

  int rx = (r & 7) << 4;
  int nt = K >> 6;

  stage(0, 0);   // 8 gl_lds per wave in flight
  for (int t = 0; t < nt; ++t) {
    if (t + 1 < nt) {
      stage((t + 1) & 1, (t + 1) << 6);               // issue next (8 more)
      asm volatile("s_waitcnt vmcnt(8)" ::: "memory"); // current tile done, next in flight
    } else {
      asm volatile("s_waitcnt vmcnt(0)" ::: "memory");
    }
    __builtin_amdgcn_sched_barrier(0);
    __builtin_amdgcn_s_barrier();
    __builtin_amdgcn_sched_barrier(0);
    const char* Ab = (const char*)(smem + (t & 1) * 16384);
    const char* Bb = Ab + 16384;   // bytes (8192 shorts)
    for (int kk = 0; kk < 2; ++kk) {
      bf16x8 af[4], bfv[4];
      for (int mi = 0; mi < 4; ++mi)
        af[mi] = *(const bf16x8*)(Ab + (size_t)(wr * 64 + mi * 16 + r) * 128 +
                                  ((kk * 64 + g * 16) ^ rx));
      for (int ni = 0; ni < 4; ++ni)
        bfv[ni] = *(const bf16x8*)(Bb + (size_t)(wc * 64 + ni * 16 + r) * 128 +
                                   ((kk * 64 + g * 16) ^ rx));
      for (int mi = 0; mi < 4; ++mi)
        for (int ni = 0; ni < 4; ++ni)
          acc[mi][ni] = mfma16(af[mi], bfv[ni], acc[mi][ni]);
    }
    __builtin_amdgcn_sched_barrier(0);
    __builtin_amdgcn_s_barrier();   // readers done -> next iter may overwrite
  }

  if (OUT_MODE == 2) {
    // transposed epilogue -> vT[bh][d][s]; smem reused as [128][136] scratch.
    for (int mi = 0; mi < 4; ++mi)
      for (int ni = 0; ni < 4; ++ni) {
        int col = wc * 64 + ni * 16 + r;
        float bv = bias[bcol + col];
        int rowb = wr * 64 + mi * 16 + g * 4;
        for (int i = 0; i < 4; ++i)
          smem[col * 136 + rowb + i] = f2bf(acc[mi][ni][i] + bv);
      }
    __syncthreads();
    int col = tid >> 1, half = tid & 1;
    int bh = (int)(brow >> 11) * 16 + (int)(bcol >> 7);
    unsigned short* outp = (unsigned short*)Cout +
                           ((size_t)bh * 128 + col) * 2048 + (brow & 2047);
    for (int j = 0; j < 8; ++j) {
      int row0 = half * 64 + j * 8;
      *(us8*)(outp + row0) = *(const us8*)&smem[col * 136 + row0];
    }
    return;
  }

  for (int mi = 0; mi < 4; ++mi)
    for (int ni = 0; ni < 4; ++ni) {
      long col = bcol + wc * 64 + ni * 16 + r;
      float bv = bias ? bias[col] : 0.0f;
      long rowb = brow + wr * 64 + mi * 16 + g * 4;
      for (int i = 0; i < 4; ++i) {
        float v = acc[mi][ni][i] + bv;
        if (OUT_MODE == 1)
          ((float*)Cout)[(rowb + i) * (long)ldc + col] = v;
        else
          ((unsigned short*)Cout)[(rowb + i) * (long)ldc + col] = f2bf(v);
      }
    }
}

// ---------- rope: posqr[4096][1024] (per-head 64) and poskr[4096][64], vectorized ----------
__global__ void rope_kernel(const unsigned short* __restrict__ tmp_q,
                            const unsigned short* __restrict__ latext,
                            const float* __restrict__ costab,
                            const float* __restrict__ sintab,
                            unsigned short* __restrict__ posqr,
                            unsigned short* __restrict__ poskr) {
  int idx = blockIdx.x * 256 + threadIdx.x;  // 524288 posq + 32768 posk = 557056
  const unsigned short* src;
  unsigned short* dst;
  int s, dp0;
  if (idx < 524288) {
    int rowA = idx >> 7, rem = idx & 127;    // rem = h*8 + dpblk
    int h = rem >> 3;
    dp0 = (rem & 7) * 8;
    s = rowA & 2047;
    src = tmp_q + (size_t)rowA * 3072 + 2048 + h * 64;
    dst = posqr + (size_t)rowA * 1024 + h * 64 + dp0;
  } else if (idx < 557056) {
    int j = idx - 524288;
    int rowA = j >> 3;
    dp0 = (j & 7) * 8;
    s = rowA & 2047;
    src = latext + (size_t)rowA * 1664 + 1536;
    dst = poskr + (size_t)rowA * 64 + dp0;
  } else {
    return;
  }
  us8 x1 = *(const us8*)(src + dp0);
  us8 x2 = *(const us8*)(src + (dp0 ^ 32));
  int f0 = dp0 & 31;
  const float* cp = costab + s * 32 + f0;
  const float* sp = sintab + s * 32 + f0;
  bool low = dp0 < 32;
  us8 o;
  for (int e = 0; e < 8; ++e) {
    float a = b2f(x1[e]), b = b2f(x2[e]);
    float v = low ? (a * cp[e] - b * sp[e]) : (a * cp[e] + b * sp[e]);
    o[e] = f2bf(v);
  }
  *(us8*)dst = o;
}

// ---------- task decode: 2560 tasks, longest-first ----------
__device__ __forceinline__ void task_decode(int t, int& qt, int& seg, int& bh) {
  if (t < 1024) {
    qt = 31 - (t >> 7); int rem = t & 127; seg = rem >> 5; bh = rem & 31;
  } else if (t < 1792) {
    int t2 = t - 1024; int qi = t2 / 96; int rem = t2 - qi * 96;
    qt = 23 - qi; seg = rem >> 5; bh = rem & 31;
  } else if (t < 2304) {
    int t3 = t - 1792; qt = 15 - (t3 >> 6); int rem = t3 & 63; seg = rem >> 5; bh = rem & 31;
  } else {
    int t4 = t - 2304; qt = 7 - (t4 >> 5); seg = 0; bh = t4 & 31;
  }
}
__device__ __forceinline__ int task_slot(int qt, int seg, int bh) {
  if (qt >= 24) return (31 - qt) * 128 + seg * 32 + bh;
  if (qt >= 16) return 1024 + (23 - qt) * 96 + seg * 32 + bh;
  return 1792 + (15 - qt) * 64 + seg * 32 + bh;
}

// ---------- persistent split-KV causal flash attention, dynamic work-stealing ----------
// Grid 1024 (guaranteed-resident). Raw s_barriers so K/V prefetch vmcnt survives
// across chunks. Row-sum l computed via ones-MFMA (kills the 16-shfl sum tree).
__global__ __launch_bounds__(256, 2)
void flash_kernel(const unsigned short* __restrict__ tmp_q,
                  const unsigned short* __restrict__ tmp_k,
                  const unsigned short* __restrict__ posqr,
                  const unsigned short* __restrict__ poskr,
                  const unsigned short* __restrict__ vT,
                  unsigned short* __restrict__ ob,
                  unsigned short* __restrict__ Opart,
                  float* __restrict__ mlbuf,
                  int* __restrict__ counter) {
  const int S = 2048;
  int tid = threadIdx.x, wave = tid >> 6, lane = tid & 63;
  int g = lane >> 4, r = lane & 15;
  const float sl2 = 1.44269504f / 13.8564064605510183f;  // log2e / sqrt(192)
  const float DEFER = 96.0f;

  __shared__ unsigned short Klds[32 * 192];   // swizzled: blk16 ^= row&7
  __shared__ unsigned short Vlds[128 * 32];   // swizzled: blk16 ^= row&3
  __shared__ unsigned short Plds[4][16][40];
  __shared__ int s_tile;
  char* Kb = (char*)Klds;
  char* Vb = (char*)Vlds;
  int rx7 = (r & 7) << 4, rx3 = (r & 3) << 4;

  // ones B-fragment (bf16 1.0 in all slots) for row-sum MFMA
  us8 onesu;
  for (int e = 0; e < 8; ++e) onesu[e] = 0x3F80;
  bf16x8 ones = *(const bf16x8*)&onesu;

  // staging slot geometry (task-independent)
  int kn_row[2], kn_seg[2];
  for (int j = 0; j < 2; ++j) {
    int slot = j * 256 + tid;
    kn_row[j] = slot >> 4;
    kn_seg[j] = slot & 15;
  }
  int kr_row = tid >> 3, kr_seg = tid & 7;
  int v_row[2], v_seg[2];
  for (int j = 0; j < 2; ++j) {
    int slot = j * 256 + tid;
    v_row[j] = slot >> 2;
    v_seg[j] = slot & 3;
  }

  for (;;) {
    if (tid == 0) s_tile = atomicAdd(counter, 1);
    __syncthreads();
    int t = s_tile;
    if (t >= 2560) return;
    int qt, seg, bh;
    task_decode(t, qt, seg, bh);
    int b = bh >> 4, h = bh & 15;
    int qbase = qt * 64;
    int cbeg = seg * 16;
    int cend = min(cbeg + 16, 2 * (qt + 1));
    size_t rb = (size_t)b * 2048;

    const unsigned short* kpn = tmp_k + rb * 2048 + h * 128;  // row stride 2048
    const unsigned short* kpr = poskr + rb * 64;              // row stride 64
    const unsigned short* vp = vT + (size_t)bh * 128 * S;

    bf16x8 qf[6];
    {
      size_t qrowA = rb + qbase + wave * 16 + r;
      const unsigned short* qn = tmp_q + qrowA * 3072 + h * 128 + g * 8;
      for (int c = 0; c < 4; ++c) qf[c] = *(const bf16x8*)(qn + c * 32);
      const unsigned short* qr_ = posqr + qrowA * 1024 + h * 64 + g * 8;
      qf[4] = *(const bf16x8*)(qr_);
      qf[5] = *(const bf16x8*)(qr_ + 32);
    }

    f32x4 acc[8];
    for (int d = 0; d < 8; ++d) acc[d] = f32x4{0.f, 0.f, 0.f, 0.f};
    f32x4 lacc = {0.f, 0.f, 0.f, 0.f};
    float m_r[4];
    for (int i = 0; i < 4; ++i) m_r[i] = -3.0e38f;

    us8 kreg[2], krope, vreg[2];
    {
      int kv0 = cbeg * 32;
      for (int j = 0; j < 2; ++j)
        kreg[j] = *(const us8*)(kpn + (size_t)(kv0 + kn_row[j]) * 2048 + kn_seg[j] * 8);
      krope = *(const us8*)(kpr + (size_t)(kv0 + kr_row) * 64 + kr_seg * 8);
      for (int j = 0; j < 2; ++j)
        vreg[j] = *(const us8*)(vp + (size_t)v_row[j] * S + kv0 + v_seg[j] * 8);
    }

    for (int ch = cbeg; ch < cend; ++ch) {
      for (int j = 0; j < 2; ++j)
        *(us8*)(Kb + (size_t)kn_row[j] * 384 +
                ((kn_seg[j] ^ (kn_row[j] & 7)) << 4)) = kreg[j];
      *(us8*)(Kb + (size_t)kr_row * 384 +
              (((16 + kr_seg) ^ (kr_row & 7)) << 4)) = krope;
      for (int j = 0; j < 2; ++j)
        *(us8*)(Vb + (size_t)v_row[j] * 64 +
                ((v_seg[j] ^ (v_row[j] & 3)) << 4)) = vreg[j];
      // own ds_writes committed, then barrier; NO vmcnt drain (prefetch survives)
      asm volatile("s_waitcnt lgkmcnt(0)" ::: "memory");
      __builtin_amdgcn_sched_barrier(0);
      __builtin_amdgcn_s_barrier();
      __builtin_amdgcn_sched_barrier(0);
      if (ch + 1 < cend) {
        int kv1 = (ch + 1) * 32;
        for (int j = 0; j < 2; ++j)
          kreg[j] = *(const us8*)(kpn + (size_t)(kv1 + kn_row[j]) * 2048 + kn_seg[j] * 8);
        krope = *(const us8*)(kpr + (size_t)(kv1 + kr_row) * 64 + kr_seg * 8);
        for (int j = 0; j < 2; ++j)
          vreg[j] = *(const us8*)(vp + (size_t)v_row[j] * S + kv1 + v_seg[j] * 8);
      }
      int kv0 = ch * 32;

      f32x4 sc0 = {0.f, 0.f, 0.f, 0.f}, sc1 = {0.f, 0.f, 0.f, 0.f};
      __builtin_amdgcn_s_setprio(1);
      for (int c = 0; c < 6; ++c) {
        bf16x8 kf0 = *(const bf16x8*)(Kb + (size_t)r * 384 + (((c * 4 + g) << 4) ^ rx7));
        sc0 = mfma16(qf[c], kf0, sc0);
      }
      for (int c = 0; c < 6; ++c) {
        bf16x8 kf1 = *(const bf16x8*)(Kb + (size_t)(16 + r) * 384 + (((c * 4 + g) << 4) ^ rx7));
        sc1 = mfma16(qf[c], kf1, sc1);
      }
      __builtin_amdgcn_s_setprio(0);

      int kj0 = kv0 + r, kj1 = kv0 + 16 + r;
      int qi0 = qbase + wave * 16 + g * 4;
      for (int i = 0; i < 4; ++i) {
        if (kj0 > qi0 + i) sc0[i] = -1e30f;
        if (kj1 > qi0 + i) sc1[i] = -1e30f;
      }

      // T13 defer-max: skip max-tree + rescale when no row grew past m + DEFER
      float tl[4];
      bool ok = true;
      for (int i = 0; i < 4; ++i) {
        tl[i] = fmaxf(sc0[i], sc1[i]);
        ok = ok && (tl[i] - m_r[i] <= DEFER);
      }
      if (!__all(ok)) {
        for (int i = 0; i < 4; ++i) {
          float tm = tl[i];
          for (int off = 1; off < 16; off <<= 1) tm = fmaxf(tm, __shfl_xor(tm, off, 64));
          float mnew = fmaxf(m_r[i], tm);
          float corr = exp2f((m_r[i] - mnew) * sl2);
          lacc[i] *= corr;
          for (int d = 0; d < 8; ++d) acc[d][i] *= corr;
          m_r[i] = mnew;
        }
      }
      float p0[4], p1[4];
      for (int i = 0; i < 4; ++i) {
        p0[i] = exp2f((sc0[i] - m_r[i]) * sl2);
        p1[i] = exp2f((sc1[i] - m_r[i]) * sl2);
      }

      for (int i = 0; i < 4; ++i) {
        Plds[wave][g * 4 + i][r] = f2bf(p0[i]);
        Plds[wave][g * 4 + i][16 + r] = f2bf(p1[i]);
      }
      bf16x8 pa = *(const bf16x8*)&Plds[wave][r][g * 8];
      __builtin_amdgcn_s_setprio(1);
      lacc = mfma16(pa, ones, lacc);   // row sums: l += P . 1
      for (int dt = 0; dt < 8; ++dt) {
        bf16x8 vf = *(const bf16x8*)(Vb + (size_t)(dt * 16 + r) * 64 + ((g << 4) ^ rx3));
        acc[dt] = mfma16(pa, vf, acc[dt]);
      }
      __builtin_amdgcn_s_setprio(0);
      __builtin_amdgcn_sched_barrier(0);
      __builtin_amdgcn_s_barrier();   // arrival only; reads consumed before MFMA issue
    }

    if (qt <= 7) {
      // single segment: normalized store
      for (int i = 0; i < 4; ++i) {
        float inv = 1.0f / lacc[i];
        int row = qbase + wave * 16 + g * 4 + i;
        size_t base = (rb + row) * 2048 + h * 128;
        for (int dt = 0; dt < 8; ++dt)
          ob[base + dt * 16 + r] = f2bf(acc[dt][i] * inv);
      }
    } else {
      // bf16 unnormalized partial + (m,l) at slot = task id
      unsigned short* op = Opart + (size_t)t * 8192;
      for (int i = 0; i < 4; ++i) {
        int row = wave * 16 + g * 4 + i;
        for (int dt = 0; dt < 8; ++dt)
          op[row * 128 + dt * 16 + r] = f2bf(acc[dt][i]);
        if (r == 0) {
          mlbuf[(size_t)t * 128 + row * 2]     = m_r[i];
          mlbuf[(size_t)t * 128 + row * 2 + 1] = lacc[i];
        }
      }
    }
  }
}

// ---------- merge partials (qt>=8) -> attn bf16 [B*S, 2048] ----------
__global__ void merge_kernel(const unsigned short* __restrict__ Opart,
                             const float* __restrict__ mlbuf,
                             unsigned short* __restrict__ ob) {
  int qt = 8 + (blockIdx.x >> 5), bh = blockIdx.x & 31;
  int b = bh >> 4, h = bh & 15;
  int tid = threadIdx.x;
  int row = tid >> 2, c0 = (tid & 3) * 32;
  const float sl2 = 1.44269504f / 13.8564064605510183f;
  int ns = (qt >= 24) ? 4 : (qt >= 16 ? 3 : 2);

  size_t slot[4];
  float m[4], l[4], w[4];
  float M = -3.0e38f;
#pragma unroll
  for (int j = 0; j < 4; ++j) {
    if (j < ns) {
      slot[j] = task_slot(qt, j, bh);
      m[j] = mlbuf[slot[j] * 128 + row * 2];
      l[j] = mlbuf[slot[j] * 128 + row * 2 + 1];
      M = fmaxf(M, m[j]);
    }
  }
  float L = 0.f;
#pragma unroll
  for (int j = 0; j < 4; ++j)
    if (j < ns) { w[j] = exp2f((m[j] - M) * sl2); L += w[j] * l[j]; }
  float invL = 1.f / L;
#pragma unroll
  for (int j = 0; j < 4; ++j) if (j < ns) w[j] *= invL;

  float o[32];
#pragma unroll
  for (int e = 0; e < 32; ++e) o[e] = 0.f;
#pragma unroll
  for (int j = 0; j < 4; ++j) {
    if (j < ns) {
      const unsigned short* pp = Opart + slot[j] * 8192 + row * 128 + c0;
      for (int blk = 0; blk < 4; ++blk) {
        us8 v = *(const us8*)(pp + blk * 8);
        for (int e = 0; e < 8; ++e) o[blk * 8 + e] += w[j] * b2f(v[e]);
      }
    }
  }
  size_t obase = ((size_t)b * 2048 + qt * 64 + row) * 2048 + h * 128 + c0;
  for (int blk = 0; blk < 4; ++blk) {
    us8 st;
    for (int e = 0; e < 8; ++e) st[e] = f2bf(o[blk * 8 + e]);
    *(us8*)(ob + obase + blk * 8) = st;
  }
}

// ---------- launcher ----------
extern "C" void kernel_launch(void* const* d_in, const int* in_sizes, int n_in,
                              void* d_out, int out_size, void* d_ws, size_t ws_size,
                              hipStream_t stream) {
  const float* x      = (const float*)d_in[0];
  const float* w_qkv  = (const float*)d_in[1];
  const float* b_qkv  = (const float*)d_in[2];
  const float* w_qup  = (const float*)d_in[3];
  const float* b_qup  = (const float*)d_in[4];
  const float* w_kup  = (const float*)d_in[5];
  const float* b_kup  = (const float*)d_in[6];
  const float* w_vup  = (const float*)d_in[7];
  const float* b_vup  = (const float*)d_in[8];
  const float* w_qpos = (const float*)d_in[9];
  const float* b_qpos = (const float*)d_in[10];
  const float* w_kpos = (const float*)d_in[11];
  const float* b_kpos = (const float*)d_in[12];
  const float* w_o    = (const float*)d_in[13];
  const float* b_o    = (const float*)d_in[14];
  (void)in_sizes; (void)n_in; (void)out_size; (void)ws_size;

  char* ws = (char*)d_ws;
  size_t off = 0;
  auto alloc = [&](size_t bytes) -> char* {
    char* p = ws + off;
    off += (bytes + 255) & ~(size_t)255;
    return p;
  };

  unsigned short* xb     = (unsigned short*)alloc(16777216);  // x bf16 [4096,2048]; reused as attn out
  unsigned short* wB1    = (unsigned short*)alloc(6815744);   // [1664,2048]
  unsigned short* wB2q   = (unsigned short*)alloc(3145728);   // [3072,512]
  unsigned short* wB2k   = (unsigned short*)alloc(2097152);   // [2048,512]
  unsigned short* wB2v   = (unsigned short*)alloc(2097152);   // [2048,512]
  unsigned short* wBo    = (unsigned short*)alloc(8388608);   // [2048,2048]
  float*          bias1  = (float*)alloc(1664 * 4);
  float*          bias2q = (float*)alloc(3072 * 4);
  float*          costab = (float*)alloc(262144);
  float*          sintab = (float*)alloc(262144);
  unsigned short* latext = (unsigned short*)alloc(13631488);  // [4096,1664]
  unsigned short* tmp_q  = (unsigned short*)alloc(25165824);  // [4096,3072]
  unsigned short* tmp_k  = (unsigned short*)alloc(16777216);  // [4096,2048]
  unsigned short* vTbuf  = (unsigned short*)alloc(16777216);  // [32,128,2048]
  unsigned short* posqr  = (unsigned short*)alloc(8388608);   // [4096,1024]
  unsigned short* poskr  = (unsigned short*)alloc(524288);    // [4096,64]
  unsigned short* Opart  = (unsigned short*)alloc(41943040);  // [2560][64][128] bf16
  float*          mlbuf  = (float*)alloc(1310720);            // [2560][64][2]
  int*            counter= (int*)alloc(256);
  unsigned short* attnb  = xb;                                // alias: xb dead after GEMM1

  // 1. misc prep
  prep_misc_kernel<<<512, 256, 0, stream>>>(b_qkv, b_kpos, b_qup, b_qpos,
                                            bias1, bias2q, costab, sintab,
                                            wB1 + (size_t)1600 * 2048);
  // 2. convert x
  convx_kernel<<<8192, 256, 0, stream>>>(x, xb, 2097152);
  // 3. weight transposes (fp32 -> bf16, [K,N] -> [N,K])
  tconv_kernel<<<dim3(48, 64), 256, 0, stream>>>(w_qkv, 1536, wB1, 2048);
  tconv_kernel<<<dim3(2, 64), 256, 0, stream>>>(w_kpos, 64, wB1 + (size_t)1536 * 2048, 2048);
  tconv_kernel<<<dim3(64, 16), 256, 0, stream>>>(w_qup, 2048, wB2q, 512);
  tconv_kernel<<<dim3(32, 16), 256, 0, stream>>>(w_qpos, 1024, wB2q + (size_t)2048 * 512, 512);
  tconv_kernel<<<dim3(64, 16), 256, 0, stream>>>(w_kup, 2048, wB2k, 512);
  tconv_kernel<<<dim3(64, 16), 256, 0, stream>>>(w_vup, 2048, wB2v, 512);
  tconv_kernel<<<dim3(64, 64), 256, 0, stream>>>(w_o, 2048, wBo, 2048);

  // 4. GEMM1: lat_ext[4096,1664] = xb @ wB1^T + bias1  (includes pos_k cols 1536..1599)
  gemm_bt_kernel<0><<<dim3(13, 32), 256, 0, stream>>>(xb, 2048, wB1, 2048,
                                                      latext, 1664, bias1, 2048);
  // 5. up-projections (K=512); v-up writes vT directly (transposed epilogue)
  gemm_bt_kernel<0><<<dim3(24, 32), 256, 0, stream>>>(latext, 1664, wB2q, 512,
                                                      tmp_q, 3072, bias2q, 512);
  gemm_bt_kernel<0><<<dim3(16, 32), 256, 0, stream>>>(latext + 512, 1664, wB2k, 512,
                                                      tmp_k, 2048, b_kup, 512);
  gemm_bt_kernel<2><<<dim3(16, 32), 256, 0, stream>>>(latext + 1024, 1664, wB2v, 512,
                                                      vTbuf, 2048, b_vup, 512);
  // 6. rope (posqr from tmp_q slice, poskr from latext slice)
  rope_kernel<<<2176, 256, 0, stream>>>(tmp_q, latext, costab, sintab, posqr, poskr);
  // 7. persistent split-KV flash attention (work-stealing, 2560 tasks, grid=resident)
  hipMemsetAsync(counter, 0, 4, stream);
  flash_kernel<<<1024, 256, 0, stream>>>(tmp_q, tmp_k, posqr, poskr, vTbuf,
                                         attnb, Opart, mlbuf, counter);
  // 8. merge partials (qt>=8) -> attnb
  merge_kernel<<<768, 256, 0, stream>>>(Opart, mlbuf, attnb);
  // 9. output projection (fp32 out + b_o)
  gemm_bt_kernel<1><<<dim3(16, 32), 256, 0, stream>>>(attnb, 2048, wBo, 2048,
                                                      d_out, 2048, b_o, 2048);
}